// Round 9
// baseline (593.733 us; speedup 1.0000x reference)
//
#include <hip/hip_runtime.h>
#include <cstdint>
#include <cstddef>

#define BB   2
#define SEQ  4096
#define DD   768
#define HH   12
#define DHH  64
#define DFFN 3072
#define NTOK (BB*SEQ)

using bf16x8 = __attribute__((ext_vector_type(8))) __bf16;
using f32x4  = __attribute__((ext_vector_type(4))) float;
typedef unsigned int u32;

#define QK_SCALE 0.18033688011112042f   // 0.125 * log2(e): folds 1/sqrt(DH) AND e->2 base swap

__device__ __forceinline__ float fast_exp2(float x) {
    return __builtin_amdgcn_exp2f(x);   // v_exp_f32: hw computes 2^x
}

__device__ __forceinline__ unsigned short f2bf(float f) {
    unsigned u = __float_as_uint(f);
    u = u + 0x7FFFu + ((u >> 16) & 1u);
    return (unsigned short)(u >> 16);
}
// truncating bf16 (1 VALU op; rel err <2^-8, fine for P matrix)
__device__ __forceinline__ unsigned short f2bf_trunc(float f) {
    return (unsigned short)(__float_as_uint(f) >> 16);
}

__device__ __forceinline__ bf16x8 ld_bf8(const unsigned short* p) {
    return *(const bf16x8*)p;   // 16B aligned by construction
}

// pack two f32x4 (k-permuted P slices) into the PV A-fragment: [a0..a3, b0..b3]
__device__ __forceinline__ bf16x8 pack_bf8(f32x4 a, f32x4 b) {
    union { u32 w[4]; bf16x8 v; } u;
    u.w[0] = (u32)f2bf_trunc(a[0]) | ((u32)f2bf_trunc(a[1]) << 16);
    u.w[1] = (u32)f2bf_trunc(a[2]) | ((u32)f2bf_trunc(a[3]) << 16);
    u.w[2] = (u32)f2bf_trunc(b[0]) | ((u32)f2bf_trunc(b[1]) << 16);
    u.w[3] = (u32)f2bf_trunc(b[2]) | ((u32)f2bf_trunc(b[3]) << 16);
    return u.v;
}
// V fragment with the SAME permuted k-order: two 8B LDS reads (m0..3 | m4..7)
__device__ __forceinline__ bf16x8 vfrag(const unsigned short* lo, const unsigned short* hi) {
    union { uint2 d[2]; bf16x8 v; } u;
    u.d[0] = *(const uint2*)lo;
    u.d[1] = *(const uint2*)hi;
    return u.v;
}

// async global->LDS, 16B per lane (m97 pattern)
__device__ __forceinline__ void gl_lds16(const unsigned short* g, unsigned short* l) {
    __builtin_amdgcn_global_load_lds(
        (const __attribute__((address_space(1))) u32*)(uintptr_t)(const void*)g,
        (__attribute__((address_space(3))) u32*)(uintptr_t)(void*)l,
        16, 0, 0);
}

// ---------------- weight prep: fused QKV transpose fp32 [R][C] -> bf16 [C][R] -------
__global__ __launch_bounds__(256) void transpose_qkv_to_bf16(
    const float* __restrict__ wq, const float* __restrict__ wk, const float* __restrict__ wv,
    unsigned short* __restrict__ dst)
{
    __shared__ float tile[32][33];
    const int z = blockIdx.z;
    const float* src = (z == 0) ? wq : (z == 1 ? wk : wv);
    const float scale = (z == 0) ? QK_SCALE : 1.0f;
    unsigned short* d = dst + (size_t)z * 768 * 768;
    const int c0 = blockIdx.x * 32, r0 = blockIdx.y * 32;
    const int tx = threadIdx.x, ty = threadIdx.y;   // block (32,8)
#pragma unroll
    for (int i = 0; i < 32; i += 8)
        tile[ty + i][tx] = src[(size_t)(r0 + ty + i) * 768 + c0 + tx];
    __syncthreads();
#pragma unroll
    for (int i = 0; i < 32; i += 8)
        d[(size_t)(c0 + ty + i) * 768 + r0 + tx] = f2bf(scale * tile[tx][ty + i]);
}

// generic transpose (for w1/w2)
__global__ __launch_bounds__(256) void transpose_f32_to_bf16(
    const float* __restrict__ src, unsigned short* __restrict__ dst, int R, int C, float scale)
{
    __shared__ float tile[32][33];
    const int c0 = blockIdx.x * 32, r0 = blockIdx.y * 32;
    const int tx = threadIdx.x, ty = threadIdx.y;   // block (32,8)
#pragma unroll
    for (int i = 0; i < 32; i += 8)
        tile[ty + i][tx] = src[(size_t)(r0 + ty + i) * C + c0 + tx];
    __syncthreads();
#pragma unroll
    for (int i = 0; i < 32; i += 8)
        dst[(size_t)(c0 + ty + i) * R + r0 + tx] = f2bf(scale * tile[tx][ty + i]);
}

__global__ void concat_bias(const float* __restrict__ bq, const float* __restrict__ bk,
                            const float* __restrict__ bv, float* __restrict__ bqkv)
{
    int i = blockIdx.x * 256 + threadIdx.x;
    if (i < 3 * DD)
        bqkv[i] = (i < DD) ? bq[i] * QK_SCALE : (i < 2 * DD ? bk[i - DD] : bv[i - 2 * DD]);
}

// ---------------- mask scan: flag=1 iff any element != 1.0f -------------------------
__global__ __launch_bounds__(256) void mask_check(const float* __restrict__ mask, int* __restrict__ flag)
{
    const size_t n = (size_t)BB * SEQ * SEQ;
    const size_t stride = (size_t)gridDim.x * 1024;
    int bad = 0;
    for (size_t i = ((size_t)blockIdx.x * 256 + threadIdx.x) * 4; i < n; i += stride) {
        float4 v = *(const float4*)&mask[i];
        bad |= (v.x != 1.f) | (v.y != 1.f) | (v.z != 1.f) | (v.w != 1.f);
    }
    if (bad) atomicOr(flag, 1);
}

// ---------------- LayerNorm (torch.std semantics: ddof=1, denom = sigma + eps) ------
__global__ __launch_bounds__(256) void ln_fused(
    const float* __restrict__ x, const float* __restrict__ add,
    const float* __restrict__ gamma, const float* __restrict__ beta,
    unsigned short* __restrict__ out_ln, float* __restrict__ x1out)
{
    const int row = blockIdx.x, t = threadIdx.x;
    const size_t base = (size_t)row * DD;
    float v[3], s = 0.f, sq = 0.f;
#pragma unroll
    for (int p = 0; p < 3; ++p) {
        int idx = t + p * 256;
        float val = x[base + idx];
        if (add) val += add[base + idx];
        v[p] = val; s += val; sq += val * val;
    }
#pragma unroll
    for (int off = 1; off < 64; off <<= 1) {
        s  += __shfl_xor(s,  off);
        sq += __shfl_xor(sq, off);
    }
    __shared__ float red[8];
    const int wave = t >> 6;
    if ((t & 63) == 0) { red[wave] = s; red[4 + wave] = sq; }
    __syncthreads();
    s  = red[0] + red[1] + red[2] + red[3];
    sq = red[4] + red[5] + red[6] + red[7];
    const float mu   = s * (1.f / 768.f);
    const float var  = fmaxf((sq - 768.f * mu * mu) * (1.f / 767.f), 0.f);
    const float rstd = 1.f / (sqrtf(var) + 1e-6f);
#pragma unroll
    for (int p = 0; p < 3; ++p) {
        int idx = t + p * 256;
        if (x1out) x1out[base + idx] = v[p];
        out_ln[base + idx] = f2bf(gamma[idx] * (v[p] - mu) * rstd + beta[idx]);
    }
}

// ---------------- bf16 GEMM v2: 2-phase double-buffered (T3-minimum) ----------------
// Same 128x128 tile, XOR source-swizzle, XCD block swizzle. k-loop restructured:
// issue gl_lds for tile t+1 into buf[n^1] BEFORE computing tile t from buf[n];
// ONE barrier per iter (compiler's vmcnt(0)-before-s_barrier drains loads that had a
// full compute phase to land, instead of zero). Race audit: buf[n^1]'s last reads
// (iter t-1) are barrier-separated from its writes (iter t); tile t's loads drained
// by end-of-iter t-1 barrier. LDS 64KB -> 2 blocks/CU (m99/m100: neutral at 4096^3;
// our shallow-K shapes are latency-exposed -> expected win, esp. FFN2 @1.5 blocks/CU).
__global__ __launch_bounds__(256) void gemm_bf16(
    const unsigned short* __restrict__ A, const unsigned short* __restrict__ Bt,
    const float* __restrict__ bias, const float* __restrict__ resid,
    unsigned short* __restrict__ outB, float* __restrict__ outF,
    int M, int N, int K, int relu)
{
    __shared__ __align__(16) unsigned short As[2][128][64];
    __shared__ __align__(16) unsigned short Bs[2][128][64];
    const int tid = threadIdx.x;
    const int lane = tid & 63, wave = tid >> 6;
    const int quad = lane >> 4, l16 = lane & 15;
    const int wm = wave >> 1, wn = wave & 1;

    // XCD-aware bijective block swizzle (nwg % 8 == 0 at every call site)
    int wg = blockIdx.y * gridDim.x + blockIdx.x;
    const int nwg = gridDim.x * gridDim.y;
    wg = (wg & 7) * (nwg >> 3) + (wg >> 3);
    const int m0 = (wg / gridDim.x) * 128, n0 = (wg % gridDim.x) * 128;

    const f32x4 fzero = {0.f, 0.f, 0.f, 0.f};
    f32x4 acc[4][4];
#pragma unroll
    for (int i = 0; i < 4; ++i)
#pragma unroll
        for (int j = 0; j < 4; ++j) acc[i][j] = fzero;

    const int r  = tid >> 3;            // 0..31: LDS row slot
    const int cg = tid & 7;             // 0..7 : LDS granule slot (16B)

#define G_STAGE(BUF_, K0_) do {                                                       \
    _Pragma("unroll")                                                                 \
    for (int rr = 0; rr < 4; ++rr) {                                                  \
        const int row = r + rr * 32;                                                  \
        const int gc8 = (cg ^ (row & 7)) * 8;                                         \
        gl_lds16(&A [(size_t)(m0 + row) * K + (K0_) + gc8], &As[BUF_][row][cg * 8]);  \
        gl_lds16(&Bt[(size_t)(n0 + row) * K + (K0_) + gc8], &Bs[BUF_][row][cg * 8]);  \
    }                                                                                 \
} while (0)

    const int nt = K >> 6;              // k-tiles of 64
    G_STAGE(0, 0);
    __syncthreads();                    // tile 0 staged (vmcnt drained by compiler)

    for (int t = 0; t < nt; ++t) {
        const int cur = t & 1;
        if (t + 1 < nt) G_STAGE(cur ^ 1, (t + 1) * 64);   // prefetch BEFORE compute
#pragma unroll
        for (int ks = 0; ks < 2; ++ks) {
            bf16x8 af[4], bfv[4];
#pragma unroll
            for (int i = 0; i < 4; ++i) {
                const int row = wm * 64 + i * 16 + l16;
                af[i] = ld_bf8(&As[cur][row][((ks * 4 + quad) ^ (row & 7)) * 8]);
            }
#pragma unroll
            for (int j = 0; j < 4; ++j) {
                const int row = wn * 64 + j * 16 + l16;
                bfv[j] = ld_bf8(&Bs[cur][row][((ks * 4 + quad) ^ (row & 7)) * 8]);
            }
#pragma unroll
            for (int i = 0; i < 4; ++i)
#pragma unroll
                for (int j = 0; j < 4; ++j)
                    acc[i][j] = __builtin_amdgcn_mfma_f32_16x16x32_bf16(af[i], bfv[j], acc[i][j], 0, 0, 0);
        }
        __syncthreads();                // reads of buf[cur] done; tile t+1 landed
    }
#undef G_STAGE

#pragma unroll
    for (int i = 0; i < 4; ++i)
#pragma unroll
        for (int j = 0; j < 4; ++j)
#pragma unroll
            for (int rr = 0; rr < 4; ++rr) {
                const int gm = m0 + wm * 64 + i * 16 + quad * 4 + rr;
                const int gn = n0 + wn * 64 + j * 16 + l16;
                float v = acc[i][j][rr] + bias[gn];
                if (relu) v = fmaxf(v, 0.f);
                if (resid) v += resid[(size_t)gm * N + gn];
                if (outF) outF[(size_t)gm * N + gn] = v;
                if (outB) outB[(size_t)gm * N + gn] = f2bf(v);
            }
}

// ---------------- V^T extraction: qkv V-cols -> vtg[bh][64][4096] -------------------
__global__ __launch_bounds__(256) void vt_extract(
    const unsigned short* __restrict__ qkv, unsigned short* __restrict__ vtg)
{
    __shared__ unsigned short tile[64][72];
    const int bh = blockIdx.x, b = bh / HH, h = bh % HH;
    const int s0 = blockIdx.y * 64;
    const int tid = threadIdx.x;
#pragma unroll
    for (int p = 0; p < 2; ++p) {
        int idx = tid + p * 256;
        int r = idx >> 3, ch8 = (idx & 7) * 8;
        *(uint4*)&tile[r][ch8] =
            *(const uint4*)&qkv[(size_t)(b * SEQ + s0 + r) * 2304 + 1536 + h * 64 + ch8];
    }
    __syncthreads();
#pragma unroll
    for (int p = 0; p < 2; ++p) {
        int idx = tid + p * 256;
        int d = idx >> 3, sc = (idx & 7) * 8;
        unsigned short tmp[8];
#pragma unroll
        for (int j = 0; j < 8; ++j) tmp[j] = tile[sc + j][d];
        *(uint4*)&vtg[((size_t)bh * 64 + d) * SEQ + s0 + sc] = *(uint4*)tmp;
    }
}

// ---------------- flash attention v12: v11 + async-STAGE split (T14) ----------------
// (unchanged from round 8 — 130us, MfmaUtil 34.8)
__global__ __launch_bounds__(256, 3) void flash_attn12(
    const unsigned short* __restrict__ qkv, const unsigned short* __restrict__ vtg,
    const float* __restrict__ mask, const int* __restrict__ maskflag,
    float* __restrict__ ctx)
{
    __shared__ __align__(16) unsigned short Ks[128][72];
    __shared__ __align__(16) unsigned short Vt[64][136];

    const int tid = threadIdx.x;
    const int lane = tid & 63, wave = tid >> 6;
    const int quad = lane >> 4, l16 = lane & 15;
    const int NT = SEQ / 128;

    // XCD-aware bijective swizzle: each XCD owns 96 consecutive work items = 3 heads.
    const int wg  = blockIdx.y * 32 + blockIdx.x;       // grid = (32, 24)
    const int swz = (wg & 7) * 96 + (wg >> 3);
    const int bh = swz >> 5, b = bh / HH, h = bh % HH;
    const int qbase = (swz & 31) * 128 + wave * 32;
    const int use_mask = *maskflag;

    bf16x8 qf[2][2];
#pragma unroll
    for (int mt = 0; mt < 2; ++mt) {
        const size_t qrow = (size_t)(b * SEQ + qbase + mt * 16 + l16) * 2304 + h * 64;
        qf[mt][0] = ld_bf8(&qkv[qrow + quad * 8]);
        qf[mt][1] = ld_bf8(&qkv[qrow + 32 + quad * 8]);
    }
    const f32x4 fzero = {0.f, 0.f, 0.f, 0.f};
    float l_run[2] = {0.f, 0.f};        // per-lane: running sum for q = l16 (its slice)
    f32x4 o[2][4];
#pragma unroll
    for (int mt = 0; mt < 2; ++mt)
#pragma unroll
        for (int r = 0; r < 4; ++r) o[mt][r] = fzero;

    const float* mbase = mask + (size_t)b * SEQ * SEQ;
    const unsigned short* kgbase = qkv + (size_t)b * SEQ * 2304 + 768 + h * 64;
    const unsigned short* vgbase = vtg + (size_t)bh * 64 * SEQ;

    // staging geometry
    const int sr  = tid >> 3, sc8 = (tid & 7) * 8;      // K: row slot, 16B col chunk
    const int vd  = tid >> 4, vc8 = (tid & 15) * 8;     // V: d row, 16B col chunk

// issue 8 global loads for k-tile at K0_ into named regs (no LDS writes)
#define LOAD_KV(K0_)                                                                  \
    kb0 = *(const uint4*)&kgbase[(size_t)((K0_) + sr +  0) * 2304 + sc8];             \
    kb1 = *(const uint4*)&kgbase[(size_t)((K0_) + sr + 32) * 2304 + sc8];             \
    kb2 = *(const uint4*)&kgbase[(size_t)((K0_) + sr + 64) * 2304 + sc8];             \
    kb3 = *(const uint4*)&kgbase[(size_t)((K0_) + sr + 96) * 2304 + sc8];             \
    vb0 = *(const uint4*)&vgbase[(size_t)(vd +  0) * SEQ + (K0_) + vc8];              \
    vb1 = *(const uint4*)&vgbase[(size_t)(vd + 16) * SEQ + (K0_) + vc8];              \
    vb2 = *(const uint4*)&vgbase[(size_t)(vd + 32) * SEQ + (K0_) + vc8];              \
    vb3 = *(const uint4*)&vgbase[(size_t)(vd + 48) * SEQ + (K0_) + vc8]

#define WRITE_KV()                                                                    \
    *(uint4*)&Ks[sr +  0][sc8] = kb0;                                                 \
    *(uint4*)&Ks[sr + 32][sc8] = kb1;                                                 \
    *(uint4*)&Ks[sr + 64][sc8] = kb2;                                                 \
    *(uint4*)&Ks[sr + 96][sc8] = kb3;                                                 \
    *(uint4*)&Vt[vd +  0][vc8] = vb0;                                                 \
    *(uint4*)&Vt[vd + 16][vc8] = vb1;                                                 \
    *(uint4*)&Vt[vd + 32][vc8] = vb2;                                                 \
    *(uint4*)&Vt[vd + 48][vc8] = vb3

// QK^T with swapped operands; shared K fragments feed both m-tiles
#define QKT_TILE() do {                                                               \
    _Pragma("unroll")                                                                 \
    for (int j = 0; j < 8; ++j) {                                                     \
        bf16x8 kf0 = ld_bf8(&Ks[j * 16 + l16][quad * 8]);                             \
        bf16x8 kf1 = ld_bf8(&Ks[j * 16 + l16][32 + quad * 8]);                        \
        st[0][j] = __builtin_amdgcn_mfma_f32_16x16x32_bf16(kf0, qf[0][0], fzero, 0, 0, 0); \
        st[0][j] = __builtin_amdgcn_mfma_f32_16x16x32_bf16(kf1, qf[0][1], st[0][j], 0, 0, 0); \
        st[1][j] = __builtin_amdgcn_mfma_f32_16x16x32_bf16(kf0, qf[1][0], fzero, 0, 0, 0); \
        st[1][j] = __builtin_amdgcn_mfma_f32_16x16x32_bf16(kf1, qf[1][1], st[1][j], 0, 0, 0); \
    }                                                                                 \
} while (0)

// PV: P from registers (permuted k-order), V via two 8B reads with matching order
#define PV_TILE() do {                                                                \
    _Pragma("unroll")                                                                 \
    for (int kk = 0; kk < 4; ++kk) {                                                  \
        bf16x8 pa0 = pack_bf8(st[0][2 * kk], st[0][2 * kk + 1]);                      \
        bf16x8 pa1 = pack_bf8(st[1][2 * kk], st[1][2 * kk + 1]);                      \
        _Pragma("unroll")                                                             \
        for (int v = 0; v < 4; ++v) {                                                 \
            const unsigned short* vrow = &Vt[v * 16 + l16][kk * 32 + quad * 4];       \
            bf16x8 vf = vfrag(vrow, vrow + 16);                                       \
            o[0][v] = __builtin_amdgcn_mfma_f32_16x16x32_bf16(pa0, vf, o[0][v], 0, 0, 0); \
            o[1][v] = __builtin_amdgcn_mfma_f32_16x16x32_bf16(pa1, vf, o[1][v], 0, 0, 0); \
        }                                                                             \
    }                                                                                 \
} while (0)

    // prologue: stage tile 0 (immediate)
    {
        uint4 kb0, kb1, kb2, kb3, vb0, vb1, vb2, vb3;
        LOAD_KV(0);
        WRITE_KV();
    }

    if (!use_mask) {
        // ======================= FAST PATH (mask == all-ones) =======================
        for (int t = 0; t < NT; ++t) {
            __syncthreads();                            // A: tile t staged & visible
            const int kn = ((t + 1) & (NT - 1)) * 128;  // next tile (wraps, in-bounds)
            uint4 kb0, kb1, kb2, kb3, vb0, vb1, vb2, vb3;
            LOAD_KV(kn);                                // async: hides under compute
            f32x4 st[2][8];
            QKT_TILE();
            // p = exp2(s); in-lane partial row-sums (lane owns q = l16)
#pragma unroll
            for (int mt = 0; mt < 2; ++mt) {
                float acc = 0.f;
#pragma unroll
                for (int j = 0; j < 8; ++j)
#pragma unroll
                    for (int r = 0; r < 4; ++r) {
                        float p = fast_exp2(st[mt][j][r]);
                        st[mt][j][r] = p;
                        acc += p;
                    }
                l_run[mt] += acc;
            }
            PV_TILE();
            __syncthreads();                            // C: Ks/Vt reads done
            if (t < NT - 1) { WRITE_KV(); }
        }
        // cross-quad completion of the deferred row-sums
#pragma unroll
        for (int mt = 0; mt < 2; ++mt) {
            l_run[mt] += __shfl_xor(l_run[mt], 16);
            l_run[mt] += __shfl_xor(l_run[mt], 32);
        }
    } else {
        // ======================= GENERAL PATH (arbitrary mult. mask) ================
        float m_run[2] = {-1e30f, -1e30f};
        for (int t = 0; t < NT; ++t) {
            const int k0 = t * 128;
            __syncthreads();                            // A: tile t staged & visible
            const int kn = ((t + 1) & (NT - 1)) * 128;
            uint4 kb0, kb1, kb2, kb3, vb0, vb1, vb2, vb3;
            LOAD_KV(kn);
            f32x4 st[2][8];
            QKT_TILE();
            // mask multiply: q = l16, s = k0 + 16j + quad*4 + r
#pragma unroll
            for (int mt = 0; mt < 2; ++mt) {
                const float* mrow =
                    &mbase[(size_t)(qbase + mt * 16 + l16) * SEQ + k0 + quad * 4];
#pragma unroll
                for (int j = 0; j < 8; ++j)
#pragma unroll
                    for (int r = 0; r < 4; ++r)
                        st[mt][j][r] *= mrow[j * 16 + r];
            }
            // online softmax per lane-q (in-lane + cross-quad shfl)
#pragma unroll
            for (int mt = 0; mt < 2; ++mt) {
                float mx = st[mt][0][0];
#pragma unroll
                for (int j = 0; j < 8; ++j)
#pragma unroll
                    for (int r = 0; r < 4; ++r) mx = fmaxf(mx, st[mt][j][r]);
                mx = fmaxf(mx, __shfl_xor(mx, 16));
                mx = fmaxf(mx, __shfl_xor(mx, 32));
                const float mnew = fmaxf(m_run[mt], mx);
                const float alpha = fast_exp2(m_run[mt] - mnew);
                float ssum = 0.f;
#pragma unroll
                for (int j = 0; j < 8; ++j)
#pragma unroll
                    for (int r = 0; r < 4; ++r) {
                        st[mt][j][r] = fast_exp2(st[mt][j][r] - mnew);
                        ssum += st[mt][j][r];
                    }
                ssum += __shfl_xor(ssum, 16);
                ssum += __shfl_xor(ssum, 32);
                l_run[mt] = l_run[mt] * alpha + ssum;
                m_run[mt] = mnew;
                // redistribute alpha from lane-q (l16) to output rows (quad*4+r)
                float aq[4];
#pragma unroll
                for (int r = 0; r < 4; ++r) aq[r] = __shfl(alpha, quad * 4 + r);
#pragma unroll
                for (int v = 0; v < 4; ++v)
#pragma unroll
                    for (int r = 0; r < 4; ++r) o[mt][v][r] *= aq[r];
            }
            PV_TILE();
            __syncthreads();                            // C: Ks/Vt reads done
            if (t < NT - 1) { WRITE_KV(); }
        }
    }
#undef LOAD_KV
#undef WRITE_KV
#undef QKT_TILE
#undef PV_TILE

    // epilogue: redistribute L from lane-q (l16) to output rows (quad*4+r), divide
#pragma unroll
    for (int mt = 0; mt < 2; ++mt) {
        float lq[4];
#pragma unroll
        for (int r = 0; r < 4; ++r) lq[r] = __shfl(l_run[mt], quad * 4 + r);
#pragma unroll
        for (int v = 0; v < 4; ++v)
#pragma unroll
            for (int r = 0; r < 4; ++r) {
                const int row = qbase + mt * 16 + quad * 4 + r;
                ctx[(size_t)(b * SEQ + row) * DD + h * 64 + v * 16 + l16] =
                    o[mt][v][r] / lq[r];
            }
    }
}

// -----------------------------------------------------------------------------------
extern "C" void kernel_launch(void* const* d_in, const int* in_sizes, int n_in,
                              void* d_out, int out_size, void* d_ws, size_t ws_size,
                              hipStream_t stream)
{
    (void)in_sizes; (void)n_in; (void)out_size; (void)ws_size;
    const float* x      = (const float*)d_in[0];
    const float* mask   = (const float*)d_in[1];
    const float* wq     = (const float*)d_in[2];
    const float* bq     = (const float*)d_in[3];
    const float* wk     = (const float*)d_in[4];
    const float* bk     = (const float*)d_in[5];
    const float* wv     = (const float*)d_in[6];
    const float* bv     = (const float*)d_in[7];
    // d_in[8]=wo, d_in[9]=bo: reference never applies out_linear — intentionally unused
    const float* w1     = (const float*)d_in[10];
    const float* b1     = (const float*)d_in[11];
    const float* w2     = (const float*)d_in[12];
    const float* b2     = (const float*)d_in[13];
    const float* gamma1 = (const float*)d_in[14];
    const float* beta1  = (const float*)d_in[15];
    const float* gamma2 = (const float*)d_in[16];
    const float* beta2  = (const float*)d_in[17];
    float* out = (float*)d_out;

    char* ws = (char*)d_ws;
    size_t off = 0;
    auto take = [&](size_t bytes) -> char* {
        char* p = ws + off;
        off = (off + bytes + 255) & ~(size_t)255;
        return p;
    };
    unsigned short* wqkvT = (unsigned short*)take((size_t)2304 * 768 * 2);
    unsigned short* w1T   = (unsigned short*)take((size_t)3072 * 768 * 2);
    unsigned short* w2T   = (unsigned short*)take((size_t)768 * 3072 * 2);
    float*          bqkv  = (float*)take(2304 * 4);
    int*            mflag = (int*)take(256);
    unsigned short* l12   = (unsigned short*)take((size_t)NTOK * DD * 2);
    unsigned short* qkv   = (unsigned short*)take((size_t)NTOK * 2304 * 2);
    float*          x1    = (float*)take((size_t)NTOK * DD * 4);
    // big region (50.3 MB): during attention = [ctx 25.2 MB | vtg 25.2 MB]; later hb.
    char*           big   = take((size_t)NTOK * DFFN * 2);
    float*          ctx   = (float*)big;
    unsigned short* vtg   = (unsigned short*)(big + (size_t)NTOK * DD * 4);
    unsigned short* hb    = (unsigned short*)big;

    (void)hipMemsetAsync(mflag, 0, 4, stream);
    mask_check<<<2048, 256, 0, stream>>>(mask, mflag);

    // weight prep (QK_SCALE = 0.125*log2e folded into wq/bq -> scores in log2 domain)
    transpose_qkv_to_bf16<<<dim3(24, 24, 3), dim3(32, 8), 0, stream>>>(wq, wk, wv, wqkvT);
    transpose_f32_to_bf16<<<dim3(96, 24), dim3(32, 8), 0, stream>>>(w1, w1T, 768, 3072, 1.0f);
    transpose_f32_to_bf16<<<dim3(24, 96), dim3(32, 8), 0, stream>>>(w2, w2T, 3072, 768, 1.0f);
    concat_bias<<<9, 256, 0, stream>>>(bq, bk, bv, bqkv);

    // LN1 -> l1 (bf16)
    ln_fused<<<NTOK, 256, 0, stream>>>(x, nullptr, gamma1, beta1, l12, nullptr);
    // fused QKV GEMM
    gemm_bf16<<<dim3(2304 / 128, NTOK / 128), 256, 0, stream>>>(
        l12, wqkvT, bqkv, nullptr, qkv, nullptr, NTOK, 2304, 768, 0);
    // V^T per head
    vt_extract<<<dim3(BB * HH, SEQ / 64), 256, 0, stream>>>(qkv, vtg);
    // flash attention v12 -> ctx fp32
    flash_attn12<<<dim3(SEQ / 128, BB * HH), 256, 0, stream>>>(qkv, vtg, mask, mflag, ctx);
    // x1 = x + ctx, LN2 -> l2 (bf16)
    ln_fused<<<NTOK, 256, 0, stream>>>(x, ctx, gamma2, beta2, l12, x1);
    // FFN1: relu(l2 @ w1 + b1) -> hb
    gemm_bf16<<<dim3(3072 / 128, NTOK / 128), 256, 0, stream>>>(
        l12, w1T, b1, nullptr, hb, nullptr, NTOK, 3072, 768, 1);
    // FFN2: hb @ w2 + b2 + x1 -> out
    gemm_bf16<<<dim3(768 / 128, NTOK / 128), 256, 0, stream>>>(
        hb, w2T, b2, x1, nullptr, out, NTOK, 768, 3072, 0);
}

// Round 10
// 563.301 us; speedup vs baseline: 1.0540x; 1.0540x over previous
//
#include <hip/hip_runtime.h>
#include <cstdint>
#include <cstddef>

#define BB   2
#define SEQ  4096
#define DD   768
#define HH   12
#define DHH  64
#define DFFN 3072
#define NTOK (BB*SEQ)

using bf16x8 = __attribute__((ext_vector_type(8))) __bf16;
using f32x4  = __attribute__((ext_vector_type(4))) float;
typedef unsigned int u32;

#define QK_SCALE 0.18033688011112042f   // 0.125 * log2(e): folds 1/sqrt(DH) AND e->2 base swap

__device__ __forceinline__ float fast_exp2(float x) {
    return __builtin_amdgcn_exp2f(x);   // v_exp_f32: hw computes 2^x
}

__device__ __forceinline__ unsigned short f2bf(float f) {
    unsigned u = __float_as_uint(f);
    u = u + 0x7FFFu + ((u >> 16) & 1u);
    return (unsigned short)(u >> 16);
}
// truncating bf16 (1 VALU op; rel err <2^-8, fine for P matrix)
__device__ __forceinline__ unsigned short f2bf_trunc(float f) {
    return (unsigned short)(__float_as_uint(f) >> 16);
}

__device__ __forceinline__ bf16x8 ld_bf8(const unsigned short* p) {
    return *(const bf16x8*)p;   // 16B aligned by construction
}

// pack two f32x4 (k-permuted P slices) into the PV A-fragment: [a0..a3, b0..b3]
__device__ __forceinline__ bf16x8 pack_bf8(f32x4 a, f32x4 b) {
    union { u32 w[4]; bf16x8 v; } u;
    u.w[0] = (u32)f2bf_trunc(a[0]) | ((u32)f2bf_trunc(a[1]) << 16);
    u.w[1] = (u32)f2bf_trunc(a[2]) | ((u32)f2bf_trunc(a[3]) << 16);
    u.w[2] = (u32)f2bf_trunc(b[0]) | ((u32)f2bf_trunc(b[1]) << 16);
    u.w[3] = (u32)f2bf_trunc(b[2]) | ((u32)f2bf_trunc(b[3]) << 16);
    return u.v;
}
// V fragment with the SAME permuted k-order: two 8B LDS reads (m0..3 | m4..7)
__device__ __forceinline__ bf16x8 vfrag(const unsigned short* lo, const unsigned short* hi) {
    union { uint2 d[2]; bf16x8 v; } u;
    u.d[0] = *(const uint2*)lo;
    u.d[1] = *(const uint2*)hi;
    return u.v;
}

// async global->LDS, 16B per lane (m97 pattern)
__device__ __forceinline__ void gl_lds16(const unsigned short* g, unsigned short* l) {
    __builtin_amdgcn_global_load_lds(
        (const __attribute__((address_space(1))) u32*)(uintptr_t)(const void*)g,
        (__attribute__((address_space(3))) u32*)(uintptr_t)(void*)l,
        16, 0, 0);
}

// ---------------- weight prep: fused QKV transpose fp32 [R][C] -> bf16 [C][R] -------
__global__ __launch_bounds__(256) void transpose_qkv_to_bf16(
    const float* __restrict__ wq, const float* __restrict__ wk, const float* __restrict__ wv,
    unsigned short* __restrict__ dst)
{
    __shared__ float tile[32][33];
    const int z = blockIdx.z;
    const float* src = (z == 0) ? wq : (z == 1 ? wk : wv);
    const float scale = (z == 0) ? QK_SCALE : 1.0f;
    unsigned short* d = dst + (size_t)z * 768 * 768;
    const int c0 = blockIdx.x * 32, r0 = blockIdx.y * 32;
    const int tx = threadIdx.x, ty = threadIdx.y;   // block (32,8)
#pragma unroll
    for (int i = 0; i < 32; i += 8)
        tile[ty + i][tx] = src[(size_t)(r0 + ty + i) * 768 + c0 + tx];
    __syncthreads();
#pragma unroll
    for (int i = 0; i < 32; i += 8)
        d[(size_t)(c0 + ty + i) * 768 + r0 + tx] = f2bf(scale * tile[tx][ty + i]);
}

// generic transpose (for w1/w2)
__global__ __launch_bounds__(256) void transpose_f32_to_bf16(
    const float* __restrict__ src, unsigned short* __restrict__ dst, int R, int C, float scale)
{
    __shared__ float tile[32][33];
    const int c0 = blockIdx.x * 32, r0 = blockIdx.y * 32;
    const int tx = threadIdx.x, ty = threadIdx.y;   // block (32,8)
#pragma unroll
    for (int i = 0; i < 32; i += 8)
        tile[ty + i][tx] = src[(size_t)(r0 + ty + i) * C + c0 + tx];
    __syncthreads();
#pragma unroll
    for (int i = 0; i < 32; i += 8)
        dst[(size_t)(c0 + ty + i) * R + r0 + tx] = f2bf(scale * tile[tx][ty + i]);
}

__global__ void concat_bias(const float* __restrict__ bq, const float* __restrict__ bk,
                            const float* __restrict__ bv, float* __restrict__ bqkv)
{
    int i = blockIdx.x * 256 + threadIdx.x;
    if (i < 3 * DD)
        bqkv[i] = (i < DD) ? bq[i] * QK_SCALE : (i < 2 * DD ? bk[i - DD] : bv[i - 2 * DD]);
}

// ---------------- mask scan: flag=1 iff any element != 1.0f -------------------------
__global__ __launch_bounds__(256) void mask_check(const float* __restrict__ mask, int* __restrict__ flag)
{
    const size_t n = (size_t)BB * SEQ * SEQ;
    const size_t stride = (size_t)gridDim.x * 1024;
    int bad = 0;
    for (size_t i = ((size_t)blockIdx.x * 256 + threadIdx.x) * 4; i < n; i += stride) {
        float4 v = *(const float4*)&mask[i];
        bad |= (v.x != 1.f) | (v.y != 1.f) | (v.z != 1.f) | (v.w != 1.f);
    }
    if (bad) atomicOr(flag, 1);
}

// ---------------- LayerNorm (torch.std semantics: ddof=1, denom = sigma + eps) ------
__global__ __launch_bounds__(256) void ln_fused(
    const float* __restrict__ x, const float* __restrict__ add,
    const float* __restrict__ gamma, const float* __restrict__ beta,
    unsigned short* __restrict__ out_ln, float* __restrict__ x1out)
{
    const int row = blockIdx.x, t = threadIdx.x;
    const size_t base = (size_t)row * DD;
    float v[3], s = 0.f, sq = 0.f;
#pragma unroll
    for (int p = 0; p < 3; ++p) {
        int idx = t + p * 256;
        float val = x[base + idx];
        if (add) val += add[base + idx];
        v[p] = val; s += val; sq += val * val;
    }
#pragma unroll
    for (int off = 1; off < 64; off <<= 1) {
        s  += __shfl_xor(s,  off);
        sq += __shfl_xor(sq, off);
    }
    __shared__ float red[8];
    const int wave = t >> 6;
    if ((t & 63) == 0) { red[wave] = s; red[4 + wave] = sq; }
    __syncthreads();
    s  = red[0] + red[1] + red[2] + red[3];
    sq = red[4] + red[5] + red[6] + red[7];
    const float mu   = s * (1.f / 768.f);
    const float var  = fmaxf((sq - 768.f * mu * mu) * (1.f / 767.f), 0.f);
    const float rstd = 1.f / (sqrtf(var) + 1e-6f);
#pragma unroll
    for (int p = 0; p < 3; ++p) {
        int idx = t + p * 256;
        if (x1out) x1out[base + idx] = v[p];
        out_ln[base + idx] = f2bf(gamma[idx] * (v[p] - mu) * rstd + beta[idx]);
    }
}

// ---------------- bf16 GEMM v3: 2-phase dbuf + COUNTED vmcnt (T4) -------------------
// Round-9's dbuf was neutral because __syncthreads drains vmcnt(0) — the end-of-iter
// barrier waited for the just-issued prefetch, nullifying it (m99/m100 replication).
// v3 uses raw s_barrier + asm s_waitcnt vmcnt(8): wait ONLY for tile t's 8 oldest
// gl_lds (vmcnt retires in issue order), leaving tile t+1's 8 in flight across the
// whole compute phase (AITER never-vmcnt(0) pattern; barrier idiom = m201 template).
// Race audit: per-wave vmcnt(8) before barrier => tile-t data visible post-barrier;
// buf[b] reads (iter t) complete before that wave's end barrier (every ds_read is
// consumed by an MFMA with compiler lgkm waits); buf[b] rewritten at iter t+2, two
// barriers later. Final iter: vmcnt(0) drain. Barrier counts uniform.
__global__ __launch_bounds__(256) void gemm_bf16(
    const unsigned short* __restrict__ A, const unsigned short* __restrict__ Bt,
    const float* __restrict__ bias, const float* __restrict__ resid,
    unsigned short* __restrict__ outB, float* __restrict__ outF,
    int M, int N, int K, int relu)
{
    __shared__ __align__(16) unsigned short As[2][128][64];
    __shared__ __align__(16) unsigned short Bs[2][128][64];
    const int tid = threadIdx.x;
    const int lane = tid & 63, wave = tid >> 6;
    const int quad = lane >> 4, l16 = lane & 15;
    const int wm = wave >> 1, wn = wave & 1;

    // XCD-aware bijective block swizzle (nwg % 8 == 0 at every call site)
    int wg = blockIdx.y * gridDim.x + blockIdx.x;
    const int nwg = gridDim.x * gridDim.y;
    wg = (wg & 7) * (nwg >> 3) + (wg >> 3);
    const int m0 = (wg / gridDim.x) * 128, n0 = (wg % gridDim.x) * 128;

    const f32x4 fzero = {0.f, 0.f, 0.f, 0.f};
    f32x4 acc[4][4];
#pragma unroll
    for (int i = 0; i < 4; ++i)
#pragma unroll
        for (int j = 0; j < 4; ++j) acc[i][j] = fzero;

    const int r  = tid >> 3;            // 0..31: LDS row slot
    const int cg = tid & 7;             // 0..7 : LDS granule slot (16B)

#define G_STAGE(BUF_, K0_) do {                                                       \
    _Pragma("unroll")                                                                 \
    for (int rr = 0; rr < 4; ++rr) {                                                  \
        const int row = r + rr * 32;                                                  \
        const int gc8 = (cg ^ (row & 7)) * 8;                                         \
        gl_lds16(&A [(size_t)(m0 + row) * K + (K0_) + gc8], &As[BUF_][row][cg * 8]);  \
        gl_lds16(&Bt[(size_t)(n0 + row) * K + (K0_) + gc8], &Bs[BUF_][row][cg * 8]);  \
    }                                                                                 \
} while (0)

    const int nt = K >> 6;              // k-tiles of 64
    G_STAGE(0, 0);                      // tile 0 in flight (8 gl_lds)

    for (int t = 0; t < nt; ++t) {
        const int cur = t & 1;
        if (t + 1 < nt) {
            G_STAGE(cur ^ 1, (t + 1) * 64);             // +8 in flight (16 total)
            asm volatile("s_waitcnt vmcnt(8)" ::: "memory");  // tile t's 8 landed
        } else {
            asm volatile("s_waitcnt vmcnt(0)" ::: "memory");  // last tile: drain
        }
        __builtin_amdgcn_s_barrier();                   // raw: no vmcnt(0) drain
#pragma unroll
        for (int ks = 0; ks < 2; ++ks) {
            bf16x8 af[4], bfv[4];
#pragma unroll
            for (int i = 0; i < 4; ++i) {
                const int row = wm * 64 + i * 16 + l16;
                af[i] = ld_bf8(&As[cur][row][((ks * 4 + quad) ^ (row & 7)) * 8]);
            }
#pragma unroll
            for (int j = 0; j < 4; ++j) {
                const int row = wn * 64 + j * 16 + l16;
                bfv[j] = ld_bf8(&Bs[cur][row][((ks * 4 + quad) ^ (row & 7)) * 8]);
            }
#pragma unroll
            for (int i = 0; i < 4; ++i)
#pragma unroll
                for (int j = 0; j < 4; ++j)
                    acc[i][j] = __builtin_amdgcn_mfma_f32_16x16x32_bf16(af[i], bfv[j], acc[i][j], 0, 0, 0);
        }
        __builtin_amdgcn_s_barrier();   // reads of buf[cur] done (lgkm consumed)
    }
#undef G_STAGE

#pragma unroll
    for (int i = 0; i < 4; ++i)
#pragma unroll
        for (int j = 0; j < 4; ++j)
#pragma unroll
            for (int rr = 0; rr < 4; ++rr) {
                const int gm = m0 + wm * 64 + i * 16 + quad * 4 + rr;
                const int gn = n0 + wn * 64 + j * 16 + l16;
                float v = acc[i][j][rr] + bias[gn];
                if (relu) v = fmaxf(v, 0.f);
                if (resid) v += resid[(size_t)gm * N + gn];
                if (outF) outF[(size_t)gm * N + gn] = v;
                if (outB) outB[(size_t)gm * N + gn] = f2bf(v);
            }
}

// ---------------- V^T extraction: qkv V-cols -> vtg[bh][64][4096] -------------------
__global__ __launch_bounds__(256) void vt_extract(
    const unsigned short* __restrict__ qkv, unsigned short* __restrict__ vtg)
{
    __shared__ unsigned short tile[64][72];
    const int bh = blockIdx.x, b = bh / HH, h = bh % HH;
    const int s0 = blockIdx.y * 64;
    const int tid = threadIdx.x;
#pragma unroll
    for (int p = 0; p < 2; ++p) {
        int idx = tid + p * 256;
        int r = idx >> 3, ch8 = (idx & 7) * 8;
        *(uint4*)&tile[r][ch8] =
            *(const uint4*)&qkv[(size_t)(b * SEQ + s0 + r) * 2304 + 1536 + h * 64 + ch8];
    }
    __syncthreads();
#pragma unroll
    for (int p = 0; p < 2; ++p) {
        int idx = tid + p * 256;
        int d = idx >> 3, sc = (idx & 7) * 8;
        unsigned short tmp[8];
#pragma unroll
        for (int j = 0; j < 8; ++j) tmp[j] = tile[sc + j][d];
        *(uint4*)&vtg[((size_t)bh * 64 + d) * SEQ + s0 + sc] = *(uint4*)tmp;
    }
}

// ---------------- flash attention v12: v11 + async-STAGE split (T14) ----------------
// (unchanged from round 8 — 130us, MfmaUtil 34.8)
__global__ __launch_bounds__(256, 3) void flash_attn12(
    const unsigned short* __restrict__ qkv, const unsigned short* __restrict__ vtg,
    const float* __restrict__ mask, const int* __restrict__ maskflag,
    float* __restrict__ ctx)
{
    __shared__ __align__(16) unsigned short Ks[128][72];
    __shared__ __align__(16) unsigned short Vt[64][136];

    const int tid = threadIdx.x;
    const int lane = tid & 63, wave = tid >> 6;
    const int quad = lane >> 4, l16 = lane & 15;
    const int NT = SEQ / 128;

    // XCD-aware bijective swizzle: each XCD owns 96 consecutive work items = 3 heads.
    const int wg  = blockIdx.y * 32 + blockIdx.x;       // grid = (32, 24)
    const int swz = (wg & 7) * 96 + (wg >> 3);
    const int bh = swz >> 5, b = bh / HH, h = bh % HH;
    const int qbase = (swz & 31) * 128 + wave * 32;
    const int use_mask = *maskflag;

    bf16x8 qf[2][2];
#pragma unroll
    for (int mt = 0; mt < 2; ++mt) {
        const size_t qrow = (size_t)(b * SEQ + qbase + mt * 16 + l16) * 2304 + h * 64;
        qf[mt][0] = ld_bf8(&qkv[qrow + quad * 8]);
        qf[mt][1] = ld_bf8(&qkv[qrow + 32 + quad * 8]);
    }
    const f32x4 fzero = {0.f, 0.f, 0.f, 0.f};
    float l_run[2] = {0.f, 0.f};        // per-lane: running sum for q = l16 (its slice)
    f32x4 o[2][4];
#pragma unroll
    for (int mt = 0; mt < 2; ++mt)
#pragma unroll
        for (int r = 0; r < 4; ++r) o[mt][r] = fzero;

    const float* mbase = mask + (size_t)b * SEQ * SEQ;
    const unsigned short* kgbase = qkv + (size_t)b * SEQ * 2304 + 768 + h * 64;
    const unsigned short* vgbase = vtg + (size_t)bh * 64 * SEQ;

    // staging geometry
    const int sr  = tid >> 3, sc8 = (tid & 7) * 8;      // K: row slot, 16B col chunk
    const int vd  = tid >> 4, vc8 = (tid & 15) * 8;     // V: d row, 16B col chunk

// issue 8 global loads for k-tile at K0_ into named regs (no LDS writes)
#define LOAD_KV(K0_)                                                                  \
    kb0 = *(const uint4*)&kgbase[(size_t)((K0_) + sr +  0) * 2304 + sc8];             \
    kb1 = *(const uint4*)&kgbase[(size_t)((K0_) + sr + 32) * 2304 + sc8];             \
    kb2 = *(const uint4*)&kgbase[(size_t)((K0_) + sr + 64) * 2304 + sc8];             \
    kb3 = *(const uint4*)&kgbase[(size_t)((K0_) + sr + 96) * 2304 + sc8];             \
    vb0 = *(const uint4*)&vgbase[(size_t)(vd +  0) * SEQ + (K0_) + vc8];              \
    vb1 = *(const uint4*)&vgbase[(size_t)(vd + 16) * SEQ + (K0_) + vc8];              \
    vb2 = *(const uint4*)&vgbase[(size_t)(vd + 32) * SEQ + (K0_) + vc8];              \
    vb3 = *(const uint4*)&vgbase[(size_t)(vd + 48) * SEQ + (K0_) + vc8]

#define WRITE_KV()                                                                    \
    *(uint4*)&Ks[sr +  0][sc8] = kb0;                                                 \
    *(uint4*)&Ks[sr + 32][sc8] = kb1;                                                 \
    *(uint4*)&Ks[sr + 64][sc8] = kb2;                                                 \
    *(uint4*)&Ks[sr + 96][sc8] = kb3;                                                 \
    *(uint4*)&Vt[vd +  0][vc8] = vb0;                                                 \
    *(uint4*)&Vt[vd + 16][vc8] = vb1;                                                 \
    *(uint4*)&Vt[vd + 32][vc8] = vb2;                                                 \
    *(uint4*)&Vt[vd + 48][vc8] = vb3

// QK^T with swapped operands; shared K fragments feed both m-tiles
#define QKT_TILE() do {                                                               \
    _Pragma("unroll")                                                                 \
    for (int j = 0; j < 8; ++j) {                                                     \
        bf16x8 kf0 = ld_bf8(&Ks[j * 16 + l16][quad * 8]);                             \
        bf16x8 kf1 = ld_bf8(&Ks[j * 16 + l16][32 + quad * 8]);                        \
        st[0][j] = __builtin_amdgcn_mfma_f32_16x16x32_bf16(kf0, qf[0][0], fzero, 0, 0, 0); \
        st[0][j] = __builtin_amdgcn_mfma_f32_16x16x32_bf16(kf1, qf[0][1], st[0][j], 0, 0, 0); \
        st[1][j] = __builtin_amdgcn_mfma_f32_16x16x32_bf16(kf0, qf[1][0], fzero, 0, 0, 0); \
        st[1][j] = __builtin_amdgcn_mfma_f32_16x16x32_bf16(kf1, qf[1][1], st[1][j], 0, 0, 0); \
    }                                                                                 \
} while (0)

// PV: P from registers (permuted k-order), V via two 8B reads with matching order
#define PV_TILE() do {                                                                \
    _Pragma("unroll")                                                                 \
    for (int kk = 0; kk < 4; ++kk) {                                                  \
        bf16x8 pa0 = pack_bf8(st[0][2 * kk], st[0][2 * kk + 1]);                      \
        bf16x8 pa1 = pack_bf8(st[1][2 * kk], st[1][2 * kk + 1]);                      \
        _Pragma("unroll")                                                             \
        for (int v = 0; v < 4; ++v) {                                                 \
            const unsigned short* vrow = &Vt[v * 16 + l16][kk * 32 + quad * 4];       \
            bf16x8 vf = vfrag(vrow, vrow + 16);                                       \
            o[0][v] = __builtin_amdgcn_mfma_f32_16x16x32_bf16(pa0, vf, o[0][v], 0, 0, 0); \
            o[1][v] = __builtin_amdgcn_mfma_f32_16x16x32_bf16(pa1, vf, o[1][v], 0, 0, 0); \
        }                                                                             \
    }                                                                                 \
} while (0)

    // prologue: stage tile 0 (immediate)
    {
        uint4 kb0, kb1, kb2, kb3, vb0, vb1, vb2, vb3;
        LOAD_KV(0);
        WRITE_KV();
    }

    if (!use_mask) {
        // ======================= FAST PATH (mask == all-ones) =======================
        for (int t = 0; t < NT; ++t) {
            __syncthreads();                            // A: tile t staged & visible
            const int kn = ((t + 1) & (NT - 1)) * 128;  // next tile (wraps, in-bounds)
            uint4 kb0, kb1, kb2, kb3, vb0, vb1, vb2, vb3;
            LOAD_KV(kn);                                // async: hides under compute
            f32x4 st[2][8];
            QKT_TILE();
            // p = exp2(s); in-lane partial row-sums (lane owns q = l16)
#pragma unroll
            for (int mt = 0; mt < 2; ++mt) {
                float acc = 0.f;
#pragma unroll
                for (int j = 0; j < 8; ++j)
#pragma unroll
                    for (int r = 0; r < 4; ++r) {
                        float p = fast_exp2(st[mt][j][r]);
                        st[mt][j][r] = p;
                        acc += p;
                    }
                l_run[mt] += acc;
            }
            PV_TILE();
            __syncthreads();                            // C: Ks/Vt reads done
            if (t < NT - 1) { WRITE_KV(); }
        }
        // cross-quad completion of the deferred row-sums
#pragma unroll
        for (int mt = 0; mt < 2; ++mt) {
            l_run[mt] += __shfl_xor(l_run[mt], 16);
            l_run[mt] += __shfl_xor(l_run[mt], 32);
        }
    } else {
        // ======================= GENERAL PATH (arbitrary mult. mask) ================
        float m_run[2] = {-1e30f, -1e30f};
        for (int t = 0; t < NT; ++t) {
            const int k0 = t * 128;
            __syncthreads();                            // A: tile t staged & visible
            const int kn = ((t + 1) & (NT - 1)) * 128;
            uint4 kb0, kb1, kb2, kb3, vb0, vb1, vb2, vb3;
            LOAD_KV(kn);
            f32x4 st[2][8];
            QKT_TILE();
            // mask multiply: q = l16, s = k0 + 16j + quad*4 + r
#pragma unroll
            for (int mt = 0; mt < 2; ++mt) {
                const float* mrow =
                    &mbase[(size_t)(qbase + mt * 16 + l16) * SEQ + k0 + quad * 4];
#pragma unroll
                for (int j = 0; j < 8; ++j)
#pragma unroll
                    for (int r = 0; r < 4; ++r)
                        st[mt][j][r] *= mrow[j * 16 + r];
            }
            // online softmax per lane-q (in-lane + cross-quad shfl)
#pragma unroll
            for (int mt = 0; mt < 2; ++mt) {
                float mx = st[mt][0][0];
#pragma unroll
                for (int j = 0; j < 8; ++j)
#pragma unroll
                    for (int r = 0; r < 4; ++r) mx = fmaxf(mx, st[mt][j][r]);
                mx = fmaxf(mx, __shfl_xor(mx, 16));
                mx = fmaxf(mx, __shfl_xor(mx, 32));
                const float mnew = fmaxf(m_run[mt], mx);
                const float alpha = fast_exp2(m_run[mt] - mnew);
                float ssum = 0.f;
#pragma unroll
                for (int j = 0; j < 8; ++j)
#pragma unroll
                    for (int r = 0; r < 4; ++r) {
                        st[mt][j][r] = fast_exp2(st[mt][j][r] - mnew);
                        ssum += st[mt][j][r];
                    }
                ssum += __shfl_xor(ssum, 16);
                ssum += __shfl_xor(ssum, 32);
                l_run[mt] = l_run[mt] * alpha + ssum;
                m_run[mt] = mnew;
                // redistribute alpha from lane-q (l16) to output rows (quad*4+r)
                float aq[4];
#pragma unroll
                for (int r = 0; r < 4; ++r) aq[r] = __shfl(alpha, quad * 4 + r);
#pragma unroll
                for (int v = 0; v < 4; ++v)
#pragma unroll
                    for (int r = 0; r < 4; ++r) o[mt][v][r] *= aq[r];
            }
            PV_TILE();
            __syncthreads();                            // C: Ks/Vt reads done
            if (t < NT - 1) { WRITE_KV(); }
        }
    }
#undef LOAD_KV
#undef WRITE_KV
#undef QKT_TILE
#undef PV_TILE

    // epilogue: redistribute L from lane-q (l16) to output rows (quad*4+r), divide
#pragma unroll
    for (int mt = 0; mt < 2; ++mt) {
        float lq[4];
#pragma unroll
        for (int r = 0; r < 4; ++r) lq[r] = __shfl(l_run[mt], quad * 4 + r);
#pragma unroll
        for (int v = 0; v < 4; ++v)
#pragma unroll
            for (int r = 0; r < 4; ++r) {
                const int row = qbase + mt * 16 + quad * 4 + r;
                ctx[(size_t)(b * SEQ + row) * DD + h * 64 + v * 16 + l16] =
                    o[mt][v][r] / lq[r];
            }
    }
}

// -----------------------------------------------------------------------------------
extern "C" void kernel_launch(void* const* d_in, const int* in_sizes, int n_in,
                              void* d_out, int out_size, void* d_ws, size_t ws_size,
                              hipStream_t stream)
{
    (void)in_sizes; (void)n_in; (void)out_size; (void)ws_size;
    const float* x      = (const float*)d_in[0];
    const float* mask   = (const float*)d_in[1];
    const float* wq     = (const float*)d_in[2];
    const float* bq     = (const float*)d_in[3];
    const float* wk     = (const float*)d_in[4];
    const float* bk     = (const float*)d_in[5];
    const float* wv     = (const float*)d_in[6];
    const float* bv     = (const float*)d_in[7];
    // d_in[8]=wo, d_in[9]=bo: reference never applies out_linear — intentionally unused
    const float* w1     = (const float*)d_in[10];
    const float* b1     = (const float*)d_in[11];
    const float* w2     = (const float*)d_in[12];
    const float* b2     = (const float*)d_in[13];
    const float* gamma1 = (const float*)d_in[14];
    const float* beta1  = (const float*)d_in[15];
    const float* gamma2 = (const float*)d_in[16];
    const float* beta2  = (const float*)d_in[17];
    float* out = (float*)d_out;

    char* ws = (char*)d_ws;
    size_t off = 0;
    auto take = [&](size_t bytes) -> char* {
        char* p = ws + off;
        off = (off + bytes + 255) & ~(size_t)255;
        return p;
    };
    unsigned short* wqkvT = (unsigned short*)take((size_t)2304 * 768 * 2);
    unsigned short* w1T   = (unsigned short*)take((size_t)3072 * 768 * 2);
    unsigned short* w2T   = (unsigned short*)take((size_t)768 * 3072 * 2);
    float*          bqkv  = (float*)take(2304 * 4);
    int*            mflag = (int*)take(256);
    unsigned short* l12   = (unsigned short*)take((size_t)NTOK * DD * 2);
    unsigned short* qkv   = (unsigned short*)take((size_t)NTOK * 2304 * 2);
    float*          x1    = (float*)take((size_t)NTOK * DD * 4);
    // big region (50.3 MB): during attention = [ctx 25.2 MB | vtg 25.2 MB]; later hb.
    char*           big   = take((size_t)NTOK * DFFN * 2);
    float*          ctx   = (float*)big;
    unsigned short* vtg   = (unsigned short*)(big + (size_t)NTOK * DD * 4);
    unsigned short* hb    = (unsigned short*)big;

    (void)hipMemsetAsync(mflag, 0, 4, stream);
    mask_check<<<2048, 256, 0, stream>>>(mask, mflag);

    // weight prep (QK_SCALE = 0.125*log2e folded into wq/bq -> scores in log2 domain)
    transpose_qkv_to_bf16<<<dim3(24, 24, 3), dim3(32, 8), 0, stream>>>(wq, wk, wv, wqkvT);
    transpose_f32_to_bf16<<<dim3(96, 24), dim3(32, 8), 0, stream>>>(w1, w1T, 768, 3072, 1.0f);
    transpose_f32_to_bf16<<<dim3(24, 96), dim3(32, 8), 0, stream>>>(w2, w2T, 3072, 768, 1.0f);
    concat_bias<<<9, 256, 0, stream>>>(bq, bk, bv, bqkv);

    // LN1 -> l1 (bf16)
    ln_fused<<<NTOK, 256, 0, stream>>>(x, nullptr, gamma1, beta1, l12, nullptr);
    // fused QKV GEMM
    gemm_bf16<<<dim3(2304 / 128, NTOK / 128), 256, 0, stream>>>(
        l12, wqkvT, bqkv, nullptr, qkv, nullptr, NTOK, 2304, 768, 0);
    // V^T per head
    vt_extract<<<dim3(BB * HH, SEQ / 64), 256, 0, stream>>>(qkv, vtg);
    // flash attention v12 -> ctx fp32
    flash_attn12<<<dim3(SEQ / 128, BB * HH), 256, 0, stream>>>(qkv, vtg, mask, mflag, ctx);
    // x1 = x + ctx, LN2 -> l2 (bf16)
    ln_fused<<<NTOK, 256, 0, stream>>>(x, ctx, gamma2, beta2, l12, x1);
    // FFN1: relu(l2 @ w1 + b1) -> hb
    gemm_bf16<<<dim3(3072 / 128, NTOK / 128), 256, 0, stream>>>(
        l12, w1T, b1, nullptr, hb, nullptr, NTOK, 3072, 768, 1);
    // FFN2: hb @ w2 + b2 + x1 -> out
    gemm_bf16<<<dim3(768 / 128, NTOK / 128), 256, 0, stream>>>(
        hb, w2T, b2, x1, nullptr, out, NTOK, 768, 3072, 0);
}

// Round 11
// 558.851 us; speedup vs baseline: 1.0624x; 1.0080x over previous
//
#include <hip/hip_runtime.h>
#include <cstdint>
#include <cstddef>

#define BB   2
#define SEQ  4096
#define DD   768
#define HH   12
#define DHH  64
#define DFFN 3072
#define NTOK (BB*SEQ)

using bf16x8 = __attribute__((ext_vector_type(8))) __bf16;
using f32x4  = __attribute__((ext_vector_type(4))) float;
typedef unsigned int u32;

#define QK_SCALE 0.18033688011112042f   // 0.125 * log2(e): folds 1/sqrt(DH) AND e->2 base swap

__device__ __forceinline__ float fast_exp2(float x) {
    return __builtin_amdgcn_exp2f(x);   // v_exp_f32: hw computes 2^x
}

__device__ __forceinline__ unsigned short f2bf(float f) {
    unsigned u = __float_as_uint(f);
    u = u + 0x7FFFu + ((u >> 16) & 1u);
    return (unsigned short)(u >> 16);
}
// truncating bf16 (1 VALU op; rel err <2^-8, fine for P matrix)
__device__ __forceinline__ unsigned short f2bf_trunc(float f) {
    return (unsigned short)(__float_as_uint(f) >> 16);
}

__device__ __forceinline__ bf16x8 ld_bf8(const unsigned short* p) {
    return *(const bf16x8*)p;   // 16B aligned by construction
}

// pack two f32x4 (k-permuted P slices) into the PV A-fragment: [a0..a3, b0..b3]
__device__ __forceinline__ bf16x8 pack_bf8(f32x4 a, f32x4 b) {
    union { u32 w[4]; bf16x8 v; } u;
    u.w[0] = (u32)f2bf_trunc(a[0]) | ((u32)f2bf_trunc(a[1]) << 16);
    u.w[1] = (u32)f2bf_trunc(a[2]) | ((u32)f2bf_trunc(a[3]) << 16);
    u.w[2] = (u32)f2bf_trunc(b[0]) | ((u32)f2bf_trunc(b[1]) << 16);
    u.w[3] = (u32)f2bf_trunc(b[2]) | ((u32)f2bf_trunc(b[3]) << 16);
    return u.v;
}
// V fragment with the SAME permuted k-order: two 8B LDS reads (m0..3 | m4..7)
__device__ __forceinline__ bf16x8 vfrag(const unsigned short* lo, const unsigned short* hi) {
    union { uint2 d[2]; bf16x8 v; } u;
    u.d[0] = *(const uint2*)lo;
    u.d[1] = *(const uint2*)hi;
    return u.v;
}
// all-ones bf16x8 (B operand for the row-sum MFMA: D[i][j] = sum_k A[i][k])
__device__ __forceinline__ bf16x8 ones_bf8() {
    union { u32 w[4]; bf16x8 v; } u;
    u.w[0] = u.w[1] = u.w[2] = u.w[3] = 0x3F803F80u;    // bf16 1.0 pair
    return u.v;
}

// async global->LDS, 16B per lane (m97 pattern)
__device__ __forceinline__ void gl_lds16(const unsigned short* g, unsigned short* l) {
    __builtin_amdgcn_global_load_lds(
        (const __attribute__((address_space(1))) u32*)(uintptr_t)(const void*)g,
        (__attribute__((address_space(3))) u32*)(uintptr_t)(void*)l,
        16, 0, 0);
}

// ---------------- weight prep: fused QKV transpose + bias concat --------------------
__global__ __launch_bounds__(256) void transpose_qkv_to_bf16(
    const float* __restrict__ wq, const float* __restrict__ wk, const float* __restrict__ wv,
    const float* __restrict__ bq, const float* __restrict__ bk, const float* __restrict__ bv,
    unsigned short* __restrict__ dst, float* __restrict__ bqkv)
{
    __shared__ float tile[32][33];
    const int z = blockIdx.z;
    const float* src = (z == 0) ? wq : (z == 1 ? wk : wv);
    const float scale = (z == 0) ? QK_SCALE : 1.0f;
    unsigned short* d = dst + (size_t)z * 768 * 768;
    const int c0 = blockIdx.x * 32, r0 = blockIdx.y * 32;
    const int tx = threadIdx.x, ty = threadIdx.y;   // block (32,8)
    // fold bias concat into block (0,0) of each z-slice (saves a launch)
    if (blockIdx.x == 0 && blockIdx.y == 0) {
        const float* bsrc = (z == 0) ? bq : (z == 1 ? bk : bv);
        const int tid = ty * 32 + tx;
        for (int i = tid; i < 768; i += 256)
            bqkv[z * 768 + i] = bsrc[i] * scale;
    }
#pragma unroll
    for (int i = 0; i < 32; i += 8)
        tile[ty + i][tx] = src[(size_t)(r0 + ty + i) * 768 + c0 + tx];
    __syncthreads();
#pragma unroll
    for (int i = 0; i < 32; i += 8)
        d[(size_t)(c0 + ty + i) * 768 + r0 + tx] = f2bf(scale * tile[tx][ty + i]);
}

// generic transpose (for w1/w2)
__global__ __launch_bounds__(256) void transpose_f32_to_bf16(
    const float* __restrict__ src, unsigned short* __restrict__ dst, int R, int C, float scale)
{
    __shared__ float tile[32][33];
    const int c0 = blockIdx.x * 32, r0 = blockIdx.y * 32;
    const int tx = threadIdx.x, ty = threadIdx.y;   // block (32,8)
#pragma unroll
    for (int i = 0; i < 32; i += 8)
        tile[ty + i][tx] = src[(size_t)(r0 + ty + i) * C + c0 + tx];
    __syncthreads();
#pragma unroll
    for (int i = 0; i < 32; i += 8)
        dst[(size_t)(c0 + ty + i) * R + r0 + tx] = f2bf(scale * tile[tx][ty + i]);
}

// ---------------- mask scan: flag=1 iff any element != 1.0f -------------------------
__global__ __launch_bounds__(256) void mask_check(const float* __restrict__ mask, int* __restrict__ flag)
{
    const size_t n = (size_t)BB * SEQ * SEQ;
    const size_t stride = (size_t)gridDim.x * 1024;
    int bad = 0;
    for (size_t i = ((size_t)blockIdx.x * 256 + threadIdx.x) * 4; i < n; i += stride) {
        float4 v = *(const float4*)&mask[i];
        bad |= (v.x != 1.f) | (v.y != 1.f) | (v.z != 1.f) | (v.w != 1.f);
    }
    if (bad) atomicOr(flag, 1);
}

// ---------------- LayerNorm (torch.std semantics: ddof=1, denom = sigma + eps) ------
__global__ __launch_bounds__(256) void ln_fused(
    const float* __restrict__ x, const float* __restrict__ add,
    const float* __restrict__ gamma, const float* __restrict__ beta,
    unsigned short* __restrict__ out_ln, float* __restrict__ x1out)
{
    const int row = blockIdx.x, t = threadIdx.x;
    const size_t base = (size_t)row * DD;
    float v[3], s = 0.f, sq = 0.f;
#pragma unroll
    for (int p = 0; p < 3; ++p) {
        int idx = t + p * 256;
        float val = x[base + idx];
        if (add) val += add[base + idx];
        v[p] = val; s += val; sq += val * val;
    }
#pragma unroll
    for (int off = 1; off < 64; off <<= 1) {
        s  += __shfl_xor(s,  off);
        sq += __shfl_xor(sq, off);
    }
    __shared__ float red[8];
    const int wave = t >> 6;
    if ((t & 63) == 0) { red[wave] = s; red[4 + wave] = sq; }
    __syncthreads();
    s  = red[0] + red[1] + red[2] + red[3];
    sq = red[4] + red[5] + red[6] + red[7];
    const float mu   = s * (1.f / 768.f);
    const float var  = fmaxf((sq - 768.f * mu * mu) * (1.f / 767.f), 0.f);
    const float rstd = 1.f / (sqrtf(var) + 1e-6f);
#pragma unroll
    for (int p = 0; p < 3; ++p) {
        int idx = t + p * 256;
        if (x1out) x1out[base + idx] = v[p];
        out_ln[base + idx] = f2bf(gamma[idx] * (v[p] - mu) * rstd + beta[idx]);
    }
}

// ---------------- bf16 GEMM v3: 2-phase dbuf + COUNTED vmcnt (T4) -------------------
// (unchanged from round 10 — the counted-vmcnt win)
__global__ __launch_bounds__(256) void gemm_bf16(
    const unsigned short* __restrict__ A, const unsigned short* __restrict__ Bt,
    const float* __restrict__ bias, const float* __restrict__ resid,
    unsigned short* __restrict__ outB, float* __restrict__ outF,
    int M, int N, int K, int relu)
{
    __shared__ __align__(16) unsigned short As[2][128][64];
    __shared__ __align__(16) unsigned short Bs[2][128][64];
    const int tid = threadIdx.x;
    const int lane = tid & 63, wave = tid >> 6;
    const int quad = lane >> 4, l16 = lane & 15;
    const int wm = wave >> 1, wn = wave & 1;

    // XCD-aware bijective block swizzle (nwg % 8 == 0 at every call site)
    int wg = blockIdx.y * gridDim.x + blockIdx.x;
    const int nwg = gridDim.x * gridDim.y;
    wg = (wg & 7) * (nwg >> 3) + (wg >> 3);
    const int m0 = (wg / gridDim.x) * 128, n0 = (wg % gridDim.x) * 128;

    const f32x4 fzero = {0.f, 0.f, 0.f, 0.f};
    f32x4 acc[4][4];
#pragma unroll
    for (int i = 0; i < 4; ++i)
#pragma unroll
        for (int j = 0; j < 4; ++j) acc[i][j] = fzero;

    const int r  = tid >> 3;            // 0..31: LDS row slot
    const int cg = tid & 7;             // 0..7 : LDS granule slot (16B)

#define G_STAGE(BUF_, K0_) do {                                                       \
    _Pragma("unroll")                                                                 \
    for (int rr = 0; rr < 4; ++rr) {                                                  \
        const int row = r + rr * 32;                                                  \
        const int gc8 = (cg ^ (row & 7)) * 8;                                         \
        gl_lds16(&A [(size_t)(m0 + row) * K + (K0_) + gc8], &As[BUF_][row][cg * 8]);  \
        gl_lds16(&Bt[(size_t)(n0 + row) * K + (K0_) + gc8], &Bs[BUF_][row][cg * 8]);  \
    }                                                                                 \
} while (0)

    const int nt = K >> 6;              // k-tiles of 64
    G_STAGE(0, 0);                      // tile 0 in flight (8 gl_lds)

    for (int t = 0; t < nt; ++t) {
        const int cur = t & 1;
        if (t + 1 < nt) {
            G_STAGE(cur ^ 1, (t + 1) * 64);             // +8 in flight (16 total)
            asm volatile("s_waitcnt vmcnt(8)" ::: "memory");  // tile t's 8 landed
        } else {
            asm volatile("s_waitcnt vmcnt(0)" ::: "memory");  // last tile: drain
        }
        __builtin_amdgcn_s_barrier();                   // raw: no vmcnt(0) drain
#pragma unroll
        for (int ks = 0; ks < 2; ++ks) {
            bf16x8 af[4], bfv[4];
#pragma unroll
            for (int i = 0; i < 4; ++i) {
                const int row = wm * 64 + i * 16 + l16;
                af[i] = ld_bf8(&As[cur][row][((ks * 4 + quad) ^ (row & 7)) * 8]);
            }
#pragma unroll
            for (int j = 0; j < 4; ++j) {
                const int row = wn * 64 + j * 16 + l16;
                bfv[j] = ld_bf8(&Bs[cur][row][((ks * 4 + quad) ^ (row & 7)) * 8]);
            }
#pragma unroll
            for (int i = 0; i < 4; ++i)
#pragma unroll
                for (int j = 0; j < 4; ++j)
                    acc[i][j] = __builtin_amdgcn_mfma_f32_16x16x32_bf16(af[i], bfv[j], acc[i][j], 0, 0, 0);
        }
        __builtin_amdgcn_s_barrier();   // reads of buf[cur] done (lgkm consumed)
    }
#undef G_STAGE

#pragma unroll
    for (int i = 0; i < 4; ++i)
#pragma unroll
        for (int j = 0; j < 4; ++j)
#pragma unroll
            for (int rr = 0; rr < 4; ++rr) {
                const int gm = m0 + wm * 64 + i * 16 + quad * 4 + rr;
                const int gn = n0 + wn * 64 + j * 16 + l16;
                float v = acc[i][j][rr] + bias[gn];
                if (relu) v = fmaxf(v, 0.f);
                if (resid) v += resid[(size_t)gm * N + gn];
                if (outF) outF[(size_t)gm * N + gn] = v;
                if (outB) outB[(size_t)gm * N + gn] = f2bf(v);
            }
}

// ---------------- V^T extraction: qkv V-cols -> vtg[bh][64][4096] -------------------
__global__ __launch_bounds__(256) void vt_extract(
    const unsigned short* __restrict__ qkv, unsigned short* __restrict__ vtg)
{
    __shared__ unsigned short tile[64][72];
    const int bh = blockIdx.x, b = bh / HH, h = bh % HH;
    const int s0 = blockIdx.y * 64;
    const int tid = threadIdx.x;
#pragma unroll
    for (int p = 0; p < 2; ++p) {
        int idx = tid + p * 256;
        int r = idx >> 3, ch8 = (idx & 7) * 8;
        *(uint4*)&tile[r][ch8] =
            *(const uint4*)&qkv[(size_t)(b * SEQ + s0 + r) * 2304 + 1536 + h * 64 + ch8];
    }
    __syncthreads();
#pragma unroll
    for (int p = 0; p < 2; ++p) {
        int idx = tid + p * 256;
        int d = idx >> 3, sc = (idx & 7) * 8;
        unsigned short tmp[8];
#pragma unroll
        for (int j = 0; j < 8; ++j) tmp[j] = tile[sc + j][d];
        *(uint4*)&vtg[((size_t)bh * 64 + d) * SEQ + s0 + sc] = *(uint4*)tmp;
    }
}

// ---------------- flash attention v13: v12 + row-sum on the matrix pipe -------------
// l = P·ones computed by one extra MFMA per kk (B = ones bf16x8, reuses the SAME pa
// fragments PV built; k-permutation irrelevant under summation). Deletes ~66 VALU
// adds/lane/tile AND the epilogue cross-quad shfl: l_acc[mt][r] is already in output
// row layout (row = quad*4+r, replicated over l16). Denominator is now the sum of
// bf16-TRUNCATED P — consistent with the numerator (same truncated P through PV).
// Mask path unchanged (converts its scalar l_run to l_acc layout at the end).
__global__ __launch_bounds__(256, 3) void flash_attn13(
    const unsigned short* __restrict__ qkv, const unsigned short* __restrict__ vtg,
    const float* __restrict__ mask, const int* __restrict__ maskflag,
    float* __restrict__ ctx)
{
    __shared__ __align__(16) unsigned short Ks[128][72];
    __shared__ __align__(16) unsigned short Vt[64][136];

    const int tid = threadIdx.x;
    const int lane = tid & 63, wave = tid >> 6;
    const int quad = lane >> 4, l16 = lane & 15;
    const int NT = SEQ / 128;

    // XCD-aware bijective swizzle: each XCD owns 96 consecutive work items = 3 heads.
    const int wg  = blockIdx.y * 32 + blockIdx.x;       // grid = (32, 24)
    const int swz = (wg & 7) * 96 + (wg >> 3);
    const int bh = swz >> 5, b = bh / HH, h = bh % HH;
    const int qbase = (swz & 31) * 128 + wave * 32;
    const int use_mask = *maskflag;

    bf16x8 qf[2][2];
#pragma unroll
    for (int mt = 0; mt < 2; ++mt) {
        const size_t qrow = (size_t)(b * SEQ + qbase + mt * 16 + l16) * 2304 + h * 64;
        qf[mt][0] = ld_bf8(&qkv[qrow + quad * 8]);
        qf[mt][1] = ld_bf8(&qkv[qrow + 32 + quad * 8]);
    }
    const f32x4 fzero = {0.f, 0.f, 0.f, 0.f};
    const bf16x8 vones = ones_bf8();
    f32x4 l_acc[2];                     // rowsum of P: l_acc[mt][r] for row quad*4+r
    f32x4 o[2][4];
#pragma unroll
    for (int mt = 0; mt < 2; ++mt) {
        l_acc[mt] = fzero;
#pragma unroll
        for (int r = 0; r < 4; ++r) o[mt][r] = fzero;
    }

    const float* mbase = mask + (size_t)b * SEQ * SEQ;
    const unsigned short* kgbase = qkv + (size_t)b * SEQ * 2304 + 768 + h * 64;
    const unsigned short* vgbase = vtg + (size_t)bh * 64 * SEQ;

    // staging geometry
    const int sr  = tid >> 3, sc8 = (tid & 7) * 8;      // K: row slot, 16B col chunk
    const int vd  = tid >> 4, vc8 = (tid & 15) * 8;     // V: d row, 16B col chunk

// issue 8 global loads for k-tile at K0_ into named regs (no LDS writes)
#define LOAD_KV(K0_)                                                                  \
    kb0 = *(const uint4*)&kgbase[(size_t)((K0_) + sr +  0) * 2304 + sc8];             \
    kb1 = *(const uint4*)&kgbase[(size_t)((K0_) + sr + 32) * 2304 + sc8];             \
    kb2 = *(const uint4*)&kgbase[(size_t)((K0_) + sr + 64) * 2304 + sc8];             \
    kb3 = *(const uint4*)&kgbase[(size_t)((K0_) + sr + 96) * 2304 + sc8];             \
    vb0 = *(const uint4*)&vgbase[(size_t)(vd +  0) * SEQ + (K0_) + vc8];              \
    vb1 = *(const uint4*)&vgbase[(size_t)(vd + 16) * SEQ + (K0_) + vc8];              \
    vb2 = *(const uint4*)&vgbase[(size_t)(vd + 32) * SEQ + (K0_) + vc8];              \
    vb3 = *(const uint4*)&vgbase[(size_t)(vd + 48) * SEQ + (K0_) + vc8]

#define WRITE_KV()                                                                    \
    *(uint4*)&Ks[sr +  0][sc8] = kb0;                                                 \
    *(uint4*)&Ks[sr + 32][sc8] = kb1;                                                 \
    *(uint4*)&Ks[sr + 64][sc8] = kb2;                                                 \
    *(uint4*)&Ks[sr + 96][sc8] = kb3;                                                 \
    *(uint4*)&Vt[vd +  0][vc8] = vb0;                                                 \
    *(uint4*)&Vt[vd + 16][vc8] = vb1;                                                 \
    *(uint4*)&Vt[vd + 32][vc8] = vb2;                                                 \
    *(uint4*)&Vt[vd + 48][vc8] = vb3

// QK^T with swapped operands; shared K fragments feed both m-tiles
#define QKT_TILE() do {                                                               \
    _Pragma("unroll")                                                                 \
    for (int j = 0; j < 8; ++j) {                                                     \
        bf16x8 kf0 = ld_bf8(&Ks[j * 16 + l16][quad * 8]);                             \
        bf16x8 kf1 = ld_bf8(&Ks[j * 16 + l16][32 + quad * 8]);                        \
        st[0][j] = __builtin_amdgcn_mfma_f32_16x16x32_bf16(kf0, qf[0][0], fzero, 0, 0, 0); \
        st[0][j] = __builtin_amdgcn_mfma_f32_16x16x32_bf16(kf1, qf[0][1], st[0][j], 0, 0, 0); \
        st[1][j] = __builtin_amdgcn_mfma_f32_16x16x32_bf16(kf0, qf[1][0], fzero, 0, 0, 0); \
        st[1][j] = __builtin_amdgcn_mfma_f32_16x16x32_bf16(kf1, qf[1][1], st[1][j], 0, 0, 0); \
    }                                                                                 \
} while (0)

// PV: P from registers (permuted k-order), V via two 8B reads with matching order.
// Extra ones-MFMA per kk accumulates the P row-sum into l_acc on the matrix pipe.
#define PV_TILE() do {                                                                \
    _Pragma("unroll")                                                                 \
    for (int kk = 0; kk < 4; ++kk) {                                                  \
        bf16x8 pa0 = pack_bf8(st[0][2 * kk], st[0][2 * kk + 1]);                      \
        bf16x8 pa1 = pack_bf8(st[1][2 * kk], st[1][2 * kk + 1]);                      \
        l_acc[0] = __builtin_amdgcn_mfma_f32_16x16x32_bf16(pa0, vones, l_acc[0], 0, 0, 0); \
        l_acc[1] = __builtin_amdgcn_mfma_f32_16x16x32_bf16(pa1, vones, l_acc[1], 0, 0, 0); \
        _Pragma("unroll")                                                             \
        for (int v = 0; v < 4; ++v) {                                                 \
            const unsigned short* vrow = &Vt[v * 16 + l16][kk * 32 + quad * 4];       \
            bf16x8 vf = vfrag(vrow, vrow + 16);                                       \
            o[0][v] = __builtin_amdgcn_mfma_f32_16x16x32_bf16(pa0, vf, o[0][v], 0, 0, 0); \
            o[1][v] = __builtin_amdgcn_mfma_f32_16x16x32_bf16(pa1, vf, o[1][v], 0, 0, 0); \
        }                                                                             \
    }                                                                                 \
} while (0)

    // prologue: stage tile 0 (immediate)
    {
        uint4 kb0, kb1, kb2, kb3, vb0, vb1, vb2, vb3;
        LOAD_KV(0);
        WRITE_KV();
    }

    if (!use_mask) {
        // ======================= FAST PATH (mask == all-ones) =======================
        for (int t = 0; t < NT; ++t) {
            __syncthreads();                            // A: tile t staged & visible
            const int kn = ((t + 1) & (NT - 1)) * 128;  // next tile (wraps, in-bounds)
            uint4 kb0, kb1, kb2, kb3, vb0, vb1, vb2, vb3;
            LOAD_KV(kn);                                // async: hides under compute
            f32x4 st[2][8];
            QKT_TILE();
            // p = exp2(s); row-sums ride the PV ones-MFMA (no VALU accumulation)
#pragma unroll
            for (int mt = 0; mt < 2; ++mt)
#pragma unroll
                for (int j = 0; j < 8; ++j)
#pragma unroll
                    for (int r = 0; r < 4; ++r)
                        st[mt][j][r] = fast_exp2(st[mt][j][r]);
            PV_TILE();
            __syncthreads();                            // C: Ks/Vt reads done
            if (t < NT - 1) { WRITE_KV(); }
        }
    } else {
        // ======================= GENERAL PATH (arbitrary mult. mask) ================
        float l_run[2] = {0.f, 0.f};
        float m_run[2] = {-1e30f, -1e30f};
        for (int t = 0; t < NT; ++t) {
            const int k0 = t * 128;
            __syncthreads();                            // A: tile t staged & visible
            const int kn = ((t + 1) & (NT - 1)) * 128;
            uint4 kb0, kb1, kb2, kb3, vb0, vb1, vb2, vb3;
            LOAD_KV(kn);
            f32x4 st[2][8];
            QKT_TILE();
            // mask multiply: q = l16, s = k0 + 16j + quad*4 + r
#pragma unroll
            for (int mt = 0; mt < 2; ++mt) {
                const float* mrow =
                    &mbase[(size_t)(qbase + mt * 16 + l16) * SEQ + k0 + quad * 4];
#pragma unroll
                for (int j = 0; j < 8; ++j)
#pragma unroll
                    for (int r = 0; r < 4; ++r)
                        st[mt][j][r] *= mrow[j * 16 + r];
            }
            // online softmax per lane-q (in-lane + cross-quad shfl)
#pragma unroll
            for (int mt = 0; mt < 2; ++mt) {
                float mx = st[mt][0][0];
#pragma unroll
                for (int j = 0; j < 8; ++j)
#pragma unroll
                    for (int r = 0; r < 4; ++r) mx = fmaxf(mx, st[mt][j][r]);
                mx = fmaxf(mx, __shfl_xor(mx, 16));
                mx = fmaxf(mx, __shfl_xor(mx, 32));
                const float mnew = fmaxf(m_run[mt], mx);
                const float alpha = fast_exp2(m_run[mt] - mnew);
                float ssum = 0.f;
#pragma unroll
                for (int j = 0; j < 8; ++j)
#pragma unroll
                    for (int r = 0; r < 4; ++r) {
                        st[mt][j][r] = fast_exp2(st[mt][j][r] - mnew);
                        ssum += st[mt][j][r];
                    }
                ssum += __shfl_xor(ssum, 16);
                ssum += __shfl_xor(ssum, 32);
                l_run[mt] = l_run[mt] * alpha + ssum;
                m_run[mt] = mnew;
                // redistribute alpha from lane-q (l16) to output rows (quad*4+r)
                float aq[4];
#pragma unroll
                for (int r = 0; r < 4; ++r) aq[r] = __shfl(alpha, quad * 4 + r);
#pragma unroll
                for (int v = 0; v < 4; ++v)
#pragma unroll
                    for (int r = 0; r < 4; ++r) o[mt][v][r] *= aq[r];
            }
            PV_TILE();                                  // l_acc unused on this path
            __syncthreads();                            // C: Ks/Vt reads done
            if (t < NT - 1) { WRITE_KV(); }
        }
        // convert scalar l_run (lane-q = l16) to l_acc output-row layout
#pragma unroll
        for (int mt = 0; mt < 2; ++mt)
#pragma unroll
            for (int r = 0; r < 4; ++r)
                l_acc[mt][r] = __shfl(l_run[mt], quad * 4 + r);
    }
#undef LOAD_KV
#undef WRITE_KV
#undef QKT_TILE
#undef PV_TILE

    // epilogue: l_acc[mt][r] is already per-output-row; divide and store
#pragma unroll
    for (int mt = 0; mt < 2; ++mt)
#pragma unroll
        for (int v = 0; v < 4; ++v)
#pragma unroll
            for (int r = 0; r < 4; ++r) {
                const int row = qbase + mt * 16 + quad * 4 + r;
                ctx[(size_t)(b * SEQ + row) * DD + h * 64 + v * 16 + l16] =
                    o[mt][v][r] / l_acc[mt][r];
            }
}

// -----------------------------------------------------------------------------------
extern "C" void kernel_launch(void* const* d_in, const int* in_sizes, int n_in,
                              void* d_out, int out_size, void* d_ws, size_t ws_size,
                              hipStream_t stream)
{
    (void)in_sizes; (void)n_in; (void)out_size; (void)ws_size;
    const float* x      = (const float*)d_in[0];
    const float* mask   = (const float*)d_in[1];
    const float* wq     = (const float*)d_in[2];
    const float* bq     = (const float*)d_in[3];
    const float* wk     = (const float*)d_in[4];
    const float* bk     = (const float*)d_in[5];
    const float* wv     = (const float*)d_in[6];
    const float* bv     = (const float*)d_in[7];
    // d_in[8]=wo, d_in[9]=bo: reference never applies out_linear — intentionally unused
    const float* w1     = (const float*)d_in[10];
    const float* b1     = (const float*)d_in[11];
    const float* w2     = (const float*)d_in[12];
    const float* b2     = (const float*)d_in[13];
    const float* gamma1 = (const float*)d_in[14];
    const float* beta1  = (const float*)d_in[15];
    const float* gamma2 = (const float*)d_in[16];
    const float* beta2  = (const float*)d_in[17];
    float* out = (float*)d_out;

    char* ws = (char*)d_ws;
    size_t off = 0;
    auto take = [&](size_t bytes) -> char* {
        char* p = ws + off;
        off = (off + bytes + 255) & ~(size_t)255;
        return p;
    };
    unsigned short* wqkvT = (unsigned short*)take((size_t)2304 * 768 * 2);
    unsigned short* w1T   = (unsigned short*)take((size_t)3072 * 768 * 2);
    unsigned short* w2T   = (unsigned short*)take((size_t)768 * 3072 * 2);
    float*          bqkv  = (float*)take(2304 * 4);
    int*            mflag = (int*)take(256);
    unsigned short* l12   = (unsigned short*)take((size_t)NTOK * DD * 2);
    unsigned short* qkv   = (unsigned short*)take((size_t)NTOK * 2304 * 2);
    float*          x1    = (float*)take((size_t)NTOK * DD * 4);
    // big region (50.3 MB): during attention = [ctx 25.2 MB | vtg 25.2 MB]; later hb.
    char*           big   = take((size_t)NTOK * DFFN * 2);
    float*          ctx   = (float*)big;
    unsigned short* vtg   = (unsigned short*)(big + (size_t)NTOK * DD * 4);
    unsigned short* hb    = (unsigned short*)big;

    (void)hipMemsetAsync(mflag, 0, 4, stream);
    mask_check<<<2048, 256, 0, stream>>>(mask, mflag);

    // weight prep (QK_SCALE = 0.125*log2e folded into wq/bq -> scores in log2 domain)
    transpose_qkv_to_bf16<<<dim3(24, 24, 3), dim3(32, 8), 0, stream>>>(
        wq, wk, wv, bq, bk, bv, wqkvT, bqkv);
    transpose_f32_to_bf16<<<dim3(96, 24), dim3(32, 8), 0, stream>>>(w1, w1T, 768, 3072, 1.0f);
    transpose_f32_to_bf16<<<dim3(24, 96), dim3(32, 8), 0, stream>>>(w2, w2T, 3072, 768, 1.0f);

    // LN1 -> l1 (bf16)
    ln_fused<<<NTOK, 256, 0, stream>>>(x, nullptr, gamma1, beta1, l12, nullptr);
    // fused QKV GEMM
    gemm_bf16<<<dim3(2304 / 128, NTOK / 128), 256, 0, stream>>>(
        l12, wqkvT, bqkv, nullptr, qkv, nullptr, NTOK, 2304, 768, 0);
    // V^T per head
    vt_extract<<<dim3(BB * HH, SEQ / 64), 256, 0, stream>>>(qkv, vtg);
    // flash attention v13 -> ctx fp32
    flash_attn13<<<dim3(SEQ / 128, BB * HH), 256, 0, stream>>>(qkv, vtg, mask, mflag, ctx);
    // x1 = x + ctx, LN2 -> l2 (bf16)
    ln_fused<<<NTOK, 256, 0, stream>>>(x, ctx, gamma2, beta2, l12, x1);
    // FFN1: relu(l2 @ w1 + b1) -> hb
    gemm_bf16<<<dim3(3072 / 128, NTOK / 128), 256, 0, stream>>>(
        l12, w1T, b1, nullptr, hb, nullptr, NTOK, 3072, 768, 1);
    // FFN2: hb @ w2 + b2 + x1 -> out
    gemm_bf16<<<dim3(768 / 128, NTOK / 128), 256, 0, stream>>>(
        hb, w2T, b2, x1, nullptr, out, NTOK, 768, 3072, 0);
}